// Round 24
// baseline (57.600 us; speedup 1.0000x reference)
//
#include <hip/hip_runtime.h>

// ---------------------------------------------------------------------------
// StickyHDPHMMVI emission log-likelihood, f16 MFMA + symmetry + mask-compact:
// out[bt,k] = c0_k - 0.5 * sum_x A[bt,x] * B[k,x]   (masked bt -> 0)
// x enumerates SYMMETRIC pair-blocks (bI<=bJ) of the 64x64 (d,e) space:
//   pair pb=(bI,bJ), chunks c = pb*2+p (p=0,1), slot s = g*8+q:
//     d = bI*8 + p*4 + g, e = bJ*8 + q
//     A = S0[d][e] (mu muT + F FT),  B = E_k[d][e] * (bI<bJ ? 2 : 1)
//   c=72,73: A = mu[t],  B = -2*v_k[t];  c=74,75: A = var[t], B = E_k[t,t]
// B lane-ordered: BG[((c*3 + j)*64 + kc*4 + g)*8 + q], k = j*16+kc
// k cols 0..31 via TWO MFMA; k=32 via 4x v_dot2 + shfl g-reduce (r18).
// Compaction -> full permutation idxb; inactive tiles zero-fill + exit (r21).
// Main: 4 waves/block, 19-chunk chain each (r23).
// r24: prep GJ does FOUR pivots per barrier round (16 rounds; r22 had 32).
// Per round: 4x4 pivot submatrix R + representation M over published rows;
// per-thread sequential coefs c_i = f[i]*rcp(R[i][i]) (0 on own pivot),
// a += c_i*M[i]; uniform Jordan update of R/M for t != i. Pivot-row threads'
// paths coincide with the uniform update (same verification as r22's 2x2).
// Refuted-null pile: addressing(r13), reg budget(r15), forced occupancy
// (r11 spill storm), L1 pairing(r16), LDS ring(r17), chain-halving(r23 ~2us).
// ---------------------------------------------------------------------------

#define BT_TOTAL 32768
#define BT_BLK 16
#define NCHUNK 76

typedef _Float16 f16;
typedef __attribute__((ext_vector_type(8))) _Float16 f16x8;
typedef __attribute__((ext_vector_type(4))) _Float16 f16x4;
typedef __attribute__((ext_vector_type(2))) _Float16 h2;
typedef __attribute__((ext_vector_type(4))) float f32x4;
typedef struct { h2 p[4]; } h2q;

#if __has_builtin(__builtin_amdgcn_fdot2)
#define DOT2(a, b, c) __builtin_amdgcn_fdot2((a), (b), (c), false)
#else
#define DOT2(a, b, c) fmaf((float)(a)[0], (float)(b)[0], fmaf((float)(a)[1], (float)(b)[1], (c)))
#endif

// pair-block tables (bJ outer 0..7, bI inner 0..bJ), +1 guard entry
__constant__ unsigned char PB_BJ[37] =
  {0, 1,1, 2,2,2, 3,3,3,3, 4,4,4,4,4, 5,5,5,5,5,5, 6,6,6,6,6,6,6, 7,7,7,7,7,7,7,7, 7};
__constant__ unsigned char PB_BI[37] =
  {0, 0,1, 0,1,2, 0,1,2,3, 0,1,2,3,4, 0,1,2,3,4,5, 0,1,2,3,4,5,6, 0,1,2,3,4,5,6,7, 7};

__device__ __forceinline__ float digammaf_(float x){
  float r = 0.f;
  while (x < 6.f){ r -= 1.f / x; x += 1.f; }
  float xi = 1.f / x;
  float xi2 = xi * xi;
  return r + logf(x) - 0.5f * xi
         - xi2 * (0.083333333333f - xi2 * (0.0083333333333f - xi2 * 0.0039682539683f));
}

__device__ __forceinline__ float wsum64(float x){
  #pragma unroll
  for (int o = 32; o > 0; o >>= 1) x += __shfl_down(x, o);
  return x;  // valid in lane 0
}

// ---------- kernel A: per-k prep (blocks 0..32) + mask compact (block 33) ---
__global__ __launch_bounds__(256) void prep_kernel(
    const float* __restrict__ mu_k, const float* __restrict__ Psi,
    const float* __restrict__ nu_a, const float* __restrict__ kap_a,
    const unsigned char* __restrict__ maskb,
    f16* __restrict__ BG, float* __restrict__ c0o,
    int* __restrict__ nactp, int* __restrict__ idxb)
{
  const int tid = threadIdx.x;

  if (blockIdx.x == 33){
    // ---- mask compaction: full permutation (active then inactive) ----
    __shared__ int cnts[256];
    const int l = tid & 63;
    const bool byteMask =
        __any((maskb[4 * l + 1] | maskb[4 * l + 2] | maskb[4 * l + 3]) != 0);
    unsigned int nz[32];            // bit s of nz[j] = flag of bt 4j+s
    int cnt = 0;
    if (byteMask){
      const uint4* mv = (const uint4*)(maskb + (size_t)tid * 128);
      #pragma unroll
      for (int j = 0; j < 8; ++j){
        uint4 v = mv[j];
        unsigned int w0 = v.x, w1 = v.y, w2 = v.z, w3 = v.w;
        unsigned int b0 = ((w0 & 0xFFu) != 0) | (((w0 & 0xFF00u) != 0) << 1)
                        | (((w0 & 0xFF0000u) != 0) << 2) | (((w0 & 0xFF000000u) != 0) << 3);
        unsigned int b1 = ((w1 & 0xFFu) != 0) | (((w1 & 0xFF00u) != 0) << 1)
                        | (((w1 & 0xFF0000u) != 0) << 2) | (((w1 & 0xFF000000u) != 0) << 3);
        unsigned int b2 = ((w2 & 0xFFu) != 0) | (((w2 & 0xFF00u) != 0) << 1)
                        | (((w2 & 0xFF0000u) != 0) << 2) | (((w2 & 0xFF000000u) != 0) << 3);
        unsigned int b3 = ((w3 & 0xFFu) != 0) | (((w3 & 0xFF00u) != 0) << 1)
                        | (((w3 & 0xFF0000u) != 0) << 2) | (((w3 & 0xFF000000u) != 0) << 3);
        nz[4 * j + 0] = b0; nz[4 * j + 1] = b1; nz[4 * j + 2] = b2; nz[4 * j + 3] = b3;
        cnt += __popc(b0) + __popc(b1) + __popc(b2) + __popc(b3);
      }
    } else {
      const uint4* mv = (const uint4*)maskb + (size_t)tid * 32;
      #pragma unroll
      for (int j = 0; j < 32; ++j){
        uint4 v = mv[j];
        unsigned int b = (v.x != 0) | ((v.y != 0) << 1)
                       | ((v.z != 0) << 2) | ((v.w != 0) << 3);
        nz[j] = b;
        cnt += __popc(b);
      }
    }
    cnts[tid] = cnt;
    __syncthreads();
    for (int off = 1; off < 256; off <<= 1){
      int v = cnts[tid];
      int u = (tid >= off) ? cnts[tid - off] : 0;
      __syncthreads();
      cnts[tid] = v + u;
      __syncthreads();
    }
    const int nact = cnts[255];
    const int base = tid * 128;
    int wofsA = cnts[tid] - cnt;               // exclusive active offset
    int wofsI = nact + base - wofsA;           // exclusive inactive offset
    #pragma unroll
    for (int j = 0; j < 32; ++j){
      unsigned int b = nz[j];
      #pragma unroll
      for (int s = 0; s < 4; ++s){
        const int bt = base + 4 * j + s;
        if (b & (1u << s)) idxb[wofsA++] = bt;
        else               idxb[wofsI++] = bt;
      }
    }
    if (tid == 255) *nactp = nact;
    return;
  }

  const int k = blockIdx.x;
  const int row = tid & 63;
  const int ch  = tid >> 6;        // column chunk: cols [ch*32, ch*32+32) of 128
  const int c0  = ch << 5;

  __shared__ float pr[4][2][128];  // pivot rows, double-buffered
  __shared__ float fc[4][2][64];   // f-columns,  double-buffered
  __shared__ float diag[64];
  __shared__ float muk[64];
  __shared__ float vpart[2][64];
  __shared__ float Ediag[64];

  float Wr[32];
  if (ch < 2){
    const float* Pg = Psi + (size_t)k * 4096 + (size_t)row * 64 + c0;
    #pragma unroll
    for (int c = 0; c < 32; ++c) Wr[c] = Pg[c];
  } else {
    #pragma unroll
    for (int c = 0; c < 32; ++c) Wr[c] = ((c0 - 64 + c) == row) ? 1.f : 0.f;
  }
  if (tid < 64) muk[tid] = mu_k[k * 64 + tid];
  // prologue: publish rows 0..3 and f-columns 0..3 (cols 0..3 live in ch 0)
  #pragma unroll
  for (int t = 0; t < 4; ++t){
    if (row == t){
      #pragma unroll
      for (int c = 0; c < 32; ++c) pr[t][0][c0 + c] = Wr[c];
    }
  }
  if (ch == 0){
    #pragma unroll
    for (int t = 0; t < 4; ++t) fc[t][0][row] = Wr[t];
  }
  __syncthreads();

  // ---- four-pivot Gauss-Jordan: 16 barrier rounds ----
  #pragma unroll
  for (int m = 0; m < 16; ++m){
    const int j = 4 * m;
    const int cur = m & 1, nxt = cur ^ 1;
    // load 4x4 pivot submatrix (uniform scalars) and per-thread f-state
    float R[4][4], M[4][4];
    #pragma unroll
    for (int i = 0; i < 4; ++i){
      #pragma unroll
      for (int c = 0; c < 4; ++c){
        R[i][c] = pr[i][cur][j + c];
        M[i][c] = (i == c) ? 1.f : 0.f;
      }
    }
    float f[4], a[4] = {0.f, 0.f, 0.f, 0.f};
    #pragma unroll
    for (int i = 0; i < 4; ++i) f[i] = fc[i][cur][row];

    #pragma unroll
    for (int i = 0; i < 4; ++i){
      const float piv = R[i][i];
      const float rcp = __builtin_amdgcn_rcpf(piv);
      if (tid == 0) diag[j + i] = piv;
      const float cthr = (row == j + i) ? 0.f : f[i] * rcp;
      #pragma unroll
      for (int t = 0; t < 4; ++t) a[t] = fmaf(cthr, M[i][t], a[t]);
      #pragma unroll
      for (int c2 = 0; c2 < 4; ++c2)
        if (c2 > i) f[c2] = fmaf(-cthr, R[i][c2], f[c2]);
      // uniform Jordan update of the other pivot rows
      #pragma unroll
      for (int t = 0; t < 4; ++t){
        if (t != i){
          const float ct = R[t][i] * rcp;
          #pragma unroll
          for (int c2 = 0; c2 < 4; ++c2){
            R[t][c2] = fmaf(-ct, R[i][c2], R[t][c2]);
            M[t][c2] = fmaf(-ct, M[i][c2], M[t][c2]);
          }
        }
      }
    }
    // apply: Wr -= sum_t a[t] * P_t
    #pragma unroll
    for (int c = 0; c < 32; ++c){
      float w = Wr[c];
      w = fmaf(-a[0], pr[0][cur][c0 + c], w);
      w = fmaf(-a[1], pr[1][cur][c0 + c], w);
      w = fmaf(-a[2], pr[2][cur][c0 + c], w);
      w = fmaf(-a[3], pr[3][cur][c0 + c], w);
      Wr[c] = w;
    }
    // publish rows j+4..j+7 and their f-columns
    if (m < 15){
      const int jn = j + 4;
      #pragma unroll
      for (int t = 0; t < 4; ++t){
        if (row == jn + t){
          #pragma unroll
          for (int c = 0; c < 32; ++c) pr[t][nxt][c0 + c] = Wr[c];
        }
        if (ch == ((jn + t) >> 5)) fc[t][nxt][row] = Wr[(jn + t) & 31];
      }
    }
    __syncthreads();
  }

  const float nu = nu_a[k];
  const int j_k = k >> 4, kck = k & 15;

  if (ch >= 2){
    const int h = ch - 2;                   // e-half this thread owns
    const float dinv = nu / diag[row];
    float vp = 0.f;
    #pragma unroll
    for (int c = 0; c < 32; ++c) vp = fmaf(Wr[c], muk[h * 32 + c], vp);
    vpart[h][row] = vp * dinv;
    // E-row scatter into symmetric pair-block layout (only bI <= bJ stored)
    const int d = row;
    const int bI = d >> 3;
    const int pch = (d >> 2) & 1;
    const int sHi = d & 3;                  // g-slot
    #pragma unroll
    for (int cc = 0; cc < 32; ++cc){
      const int e = h * 32 + cc;
      const int bJ = e >> 3;
      float val = Wr[cc] * dinv;
      if (e == d) Ediag[row] = val;
      if (bI <= bJ){
        const int pb = ((bJ * (bJ + 1)) >> 1) + bI;
        const int ci = pb * 2 + pch;
        const float sc = (bI < bJ) ? 2.f : 1.f;
        BG[(size_t)((ci * 3 + j_k) * 64 + kck * 4 + sHi) * 8 + (e & 7)] = (f16)(val * sc);
      }
    }
  }
  __syncthreads();

  if (tid < 64){
    const int t = tid;
    float v = vpart[0][t] + vpart[1][t];
    const int g = (t >> 3) & 3, q = t & 7;
    const int cA = 72 + (t >> 5);
    const int cB = 74 + (t >> 5);
    BG[(size_t)((cA * 3 + j_k) * 64 + kck * 4 + g) * 8 + q] = (f16)(-2.f * v);
    BG[(size_t)((cB * 3 + j_k) * 64 + kck * 4 + g) * 8 + q] = (f16)(Ediag[t]);
    float c2 = wsum64(v * muk[t]);
    float dg = wsum64(digammaf_((nu - (float)t) * 0.5f));
    float ld = wsum64(logf(diag[t]));
    if (t == 0){
      const float LN2   = 0.69314718055994531f;
      const float LN2PI = 1.83787706640934548f;
      float Elogdet = dg + 64.f * LN2 - ld;
      float cst = 0.5f * (Elogdet - 64.f * LN2PI);
      c0o[k] = cst - 0.5f * c2 - 32.f / kap_a[k];
    }
  }
}

// -------- kernel B: main (f16 MFMA x2 + k32 dot, 4-wave, compacted) ---------
#define BUILD(AF, FD, MUD)                                                 \
  {                                                                        \
    float s_[8];                                                           \
    _Pragma("unroll")                                                      \
    for (int q_ = 0; q_ < 8; ++q_) s_[q_] = (MUD) * mue[q_];               \
    _Pragma("unroll")                                                      \
    for (int r_ = 0; r_ < 4; ++r_){                                        \
      h2 fp_ = { (FD)[2 * r_], (FD)[2 * r_ + 1] };                         \
      _Pragma("unroll")                                                    \
      for (int q_ = 0; q_ < 8; ++q_){                                      \
        h2 ep_ = { FeT[q_][2 * r_], FeT[q_][2 * r_ + 1] };                 \
        s_[q_] = DOT2(fp_, ep_, s_[q_]);                                   \
      }                                                                    \
    }                                                                      \
    _Pragma("unroll")                                                      \
    for (int q_ = 0; q_ < 8; ++q_) (AF)[q_] = (f16)s_[q_];                 \
  }

#define MFMA2(AF, B0, B1)                                                  \
  acc0 = __builtin_amdgcn_mfma_f32_16x16x32_f16((AF), (B0), acc0, 0, 0, 0);\
  acc1 = __builtin_amdgcn_mfma_f32_16x16x32_f16((AF), (B1), acc1, 0, 0, 0);

#define K32DOT(AF, B32)                                                    \
  {                                                                        \
    h2q afq_ = __builtin_bit_cast(h2q, (AF));                              \
    h2q bq_  = __builtin_bit_cast(h2q, (B32));                             \
    _Pragma("unroll")                                                      \
    for (int r_ = 0; r_ < 4; ++r_)                                         \
      acc32 = DOT2(afq_.p[r_], bq_.p[r_], acc32);                          \
  }

__global__ __launch_bounds__(256, 2) void main_kernel(
    const float* __restrict__ mu_t, const float* __restrict__ var_t,
    const float* __restrict__ F_t,
    const f16* __restrict__ BG, const float* __restrict__ c0o,
    const int* __restrict__ nactp, const int* __restrict__ idxb,
    float* __restrict__ out)
{
  __shared__ __align__(16) f16 sG[BT_BLK][64][8];  // F[d][r], d^(bt&7); 16384 B
  __shared__ __align__(16) f16 sMu[BT_BLK][64];    // block-8 d-swizzle;  2048 B
  __shared__ int sIdx[BT_BLK];

  const int tid = threadIdx.x;
  const int l = tid & 63;
  const int w = tid >> 6;                // wave = pair-range quarter (0..3)
  const int g = l >> 4;
  const int kc = l & 15;
  const int btl = kc;                    // this lane's local A row
  const int btSw = btl & 7;

  const int nact = *nactp;
  const int t0 = blockIdx.x * BT_BLK;
  const int nLoc = min(BT_BLK, max(0, nact - t0));   // active rows in tile

  if (tid < BT_BLK) sIdx[tid] = idxb[t0 + tid];      // full list: always valid
  __syncthreads();

  // ---- zero-fill inactive rows of this tile (rows nLoc..16) ----
  for (int i = tid; i < (BT_BLK - nLoc) * 33; i += 256){
    const int r = nLoc + i / 33;
    out[(size_t)sIdx[r] * 33 + (i % 33)] = 0.f;
  }
  if (nLoc == 0) return;                 // fully inactive tile: done

  // ---- stage F / mu into LDS (coalesced per row, f32->f16, via idx) ----
  {
    #pragma unroll
    for (int ii = 0; ii < 8; ++ii){
      int i = tid + ii * 256;
      int bt = i >> 7, rem = i & 127, d = rem >> 1, rb = (rem & 1) << 2;
      const float4* fg = (const float4*)(F_t + (size_t)sIdx[bt] * 512);
      float4 f = fg[rem];
      int dsw = d ^ (bt & 7);
      f16x4 ff = { (f16)f.x, (f16)f.y, (f16)f.z, (f16)f.w };
      *(f16x4*)&sG[bt][dsw][rb] = ff;
    }
    {
      int i = tid;                       // 256 float4 = 16 rows x 16
      int bt = i >> 4, e4 = i & 15, d0 = e4 << 2;
      const float4* mg = (const float4*)(mu_t + (size_t)sIdx[bt] * 64);
      float4 m4 = mg[e4];
      int dsw = (((d0 >> 3) ^ (bt & 7)) << 3) | (d0 & 7);
      f16x4 mm = { (f16)m4.x, (f16)m4.y, (f16)m4.z, (f16)m4.w };
      *(f16x4*)&sMu[bt][dsw] = mm;
    }
  }
  __syncthreads();

  // per-wave pair range: wave w = pairs [9w, 9w+9), ext chunk 72+w
  const int ppStart = 9 * w;
  const int ppEnd   = ppStart + 9;

  f32x4 acc0 = {0.f,0.f,0.f,0.f}, acc1 = {0.f,0.f,0.f,0.f};
  float acc32 = 0.f;

  f16x8 FeT[8];      // F rows e = bJ*8+q (reloaded per bJ)
  float mue[8];

  const f16* bp   = BG + (size_t)(ppStart * 2) * 1536 + (size_t)(kc * 4 + g) * 8;
  const f16* bp32 = BG + (size_t)(ppStart * 2) * 1536 + 1024 + (size_t)g * 8;

  // prologue: stage A = chunk 2*ppStart, stage B = chunk 2*ppStart+1
  const int bI0 = PB_BI[ppStart];
  f16x8 fdA = *(const f16x8*)&sG[btl][(bI0 * 8 + g) ^ btSw][0];
  f16x8 fdB = *(const f16x8*)&sG[btl][(bI0 * 8 + 4 + g) ^ btSw][0];
  float mudA = (float)sMu[btl][((bI0 ^ btSw) << 3) | g];
  float mudB = (float)sMu[btl][((bI0 ^ btSw) << 3) | (4 + g)];

  f16x8 a0 = *(const f16x8*)(bp);
  f16x8 a1 = *(const f16x8*)(bp + 512);
  f16x8 b0v = *(const f16x8*)(bp + 1536);
  f16x8 b1v = *(const f16x8*)(bp + 1536 + 512);
  f16x8 w0v = *(const f16x8*)(bp32);
  f16x8 w1v = *(const f16x8*)(bp32 + 1536);
  bp += 3072;
  bp32 += 3072;

  int curBJ = -1;
  for (int pp = ppStart; pp < ppEnd; ++pp){
    const int bJ = PB_BJ[pp];
    if (bJ != curBJ){
      curBJ = bJ;
      #pragma unroll
      for (int q = 0; q < 8; ++q)
        FeT[q] = *(const f16x8*)&sG[btl][((bJ << 3) + q) ^ btSw][0];
      f16x8 mr = *(const f16x8*)&sMu[btl][((bJ ^ btSw) << 3)];
      #pragma unroll
      for (int q = 0; q < 8; ++q) mue[q] = (float)mr[q];
    }
    const int bIn = PB_BI[pp + 1];
    // ---- even chunk (stage A), refill with next pair's p=0 ----
    {
      f16x8 af;
      BUILD(af, fdA, mudA);
      MFMA2(af, a0, a1);
      K32DOT(af, w0v);
      a0 = *(const f16x8*)(bp);
      a1 = *(const f16x8*)(bp + 512);
      w0v = *(const f16x8*)(bp32);
      fdA = *(const f16x8*)&sG[btl][(bIn * 8 + g) ^ btSw][0];
      mudA = (float)sMu[btl][((bIn ^ btSw) << 3) | g];
    }
    // ---- odd chunk (stage B), refill with next pair's p=1 ----
    {
      f16x8 af;
      BUILD(af, fdB, mudB);
      MFMA2(af, b0v, b1v);
      K32DOT(af, w1v);
      b0v = *(const f16x8*)(bp + 1536);
      b1v = *(const f16x8*)(bp + 1536 + 512);
      w1v = *(const f16x8*)(bp32 + 1536);
      fdB = *(const f16x8*)&sG[btl][(bIn * 8 + 4 + g) ^ btSw][0];
      mudB = (float)sMu[btl][((bIn ^ btSw) << 3) | (4 + g)];
    }
    bp += 3072;
    bp32 += 3072;
  }

  // ---- ext chunk 72+w (one per wave), ABSOLUTE addressing ----
  {
    const f16* bpe   = BG + (size_t)(72 + w) * 1536 + (size_t)(kc * 4 + g) * 8;
    const f16* bpe32 = BG + (size_t)(72 + w) * 1536 + 1024 + (size_t)g * 8;
    f16x8 af;
    if (w < 2){
      af = *(const f16x8*)&sMu[btl][(((w * 4 + g) ^ btSw) << 3)];
    } else {
      const float* vr = var_t + (size_t)sIdx[btl] * 64 + (w - 2) * 32 + g * 8;
      f32x4 va = *(const f32x4*)(vr);
      f32x4 vb = *(const f32x4*)(vr + 4);
      #pragma unroll
      for (int r = 0; r < 4; ++r){ af[r] = (f16)va[r]; af[4 + r] = (f16)vb[r]; }
    }
    f16x8 e0 = *(const f16x8*)(bpe);
    f16x8 e1 = *(const f16x8*)(bpe + 512);
    f16x8 e32 = *(const f16x8*)(bpe32);
    MFMA2(af, e0, e1);
    K32DOT(af, e32);
  }

  // ---- cross-wave reduce (aliased into sG after barrier) ----
  __syncthreads();                         // all waves done reading sG/sMu
  float* sRedF = (float*)sG;               // [3][64][9] floats = 6912 B
  if (w > 0){
    const int bofs = ((w - 1) * 64 + l) * 9;
    #pragma unroll
    for (int r = 0; r < 4; ++r){
      sRedF[bofs + r]     = acc0[r];
      sRedF[bofs + 4 + r] = acc1[r];
    }
    sRedF[bofs + 8] = acc32;
  }
  __syncthreads();
  if (w == 0){
    #pragma unroll
    for (int ww = 0; ww < 3; ++ww){
      const int bofs = (ww * 64 + l) * 9;
      #pragma unroll
      for (int r = 0; r < 4; ++r){
        acc0[r] += sRedF[bofs + r];
        acc1[r] += sRedF[bofs + 4 + r];
      }
      acc32 += sRedF[bofs + 8];
    }
    // g-reduce k32 (lanes same kc, different g)
    acc32 += __shfl_xor(acc32, 16);
    acc32 += __shfl_xor(acc32, 32);

    float c0a = c0o[kc];
    float c0b = c0o[16 + kc];
    float c0c = c0o[32];
    #pragma unroll
    for (int reg = 0; reg < 4; ++reg){
      int r16 = g * 4 + reg;
      if (r16 < nLoc){
        float* op = out + (size_t)sIdx[r16] * 33;
        op[kc]      = fmaf(-0.5f, acc0[reg], c0a);
        op[16 + kc] = fmaf(-0.5f, acc1[reg], c0b);
      }
    }
    if (g == 0 && kc < nLoc){
      out[(size_t)sIdx[kc] * 33 + 32] = fmaf(-0.5f, acc32, c0c);
    }
  }
}

// --------------------------- launch -----------------------------------------
extern "C" void kernel_launch(void* const* d_in, const int* in_sizes, int n_in,
                              void* d_out, int out_size, void* d_ws, size_t ws_size,
                              hipStream_t stream)
{
  const float* mu_t  = (const float*)d_in[0];
  const float* var_t = (const float*)d_in[1];
  const float* F_t   = (const float*)d_in[2];
  const float* mu_k  = (const float*)d_in[3];
  const float* Psi   = (const float*)d_in[4];
  const float* nu    = (const float*)d_in[5];
  const float* kap   = (const float*)d_in[6];
  const unsigned char* mask = (const unsigned char*)d_in[7];

  f16*   BG   = (f16*)d_ws;                             // 233472 B
  float* c0o  = (float*)((char*)d_ws + 233472);         // 132 B
  int*   nact = (int*)((char*)d_ws + 233472 + 256);     // 4 B
  int*   idxb = nact + 1;                               // 131072 B
  float* outp = (float*)d_out;

  hipLaunchKernelGGL(prep_kernel, dim3(34), dim3(256), 0, stream,
                     mu_k, Psi, nu, kap, mask, BG, c0o, nact, idxb);
  hipLaunchKernelGGL(main_kernel, dim3(BT_TOTAL / BT_BLK), dim3(256), 0, stream,
                     mu_t, var_t, F_t, BG, c0o, nact, idxb, outp);
}

// Round 25
// 54.606 us; speedup vs baseline: 1.0548x; 1.0548x over previous
//
#include <hip/hip_runtime.h>

// ---------------------------------------------------------------------------
// StickyHDPHMMVI emission log-likelihood, f16 MFMA + symmetry + mask-compact:
// out[bt,k] = c0_k - 0.5 * sum_x A[bt,x] * B[k,x]   (masked bt -> 0)
// x enumerates SYMMETRIC pair-blocks (bI<=bJ) of the 64x64 (d,e) space:
//   pair pb=(bI,bJ), chunks c = pb*2+p (p=0,1), slot s = g*8+q:
//     d = bI*8 + p*4 + g, e = bJ*8 + q
//     A = S0[d][e] (mu muT + F FT),  B = E_k[d][e] * (bI<bJ ? 2 : 1)
//   c=72,73: A = mu[t],  B = -2*v_k[t];  c=74,75: A = var[t], B = E_k[t,t]
// B lane-ordered: BG[((c*3 + j)*64 + kc*4 + g)*8 + q], k = j*16+kc
// k cols 0..31 via TWO MFMA; k=32 via 4x v_dot2 + shfl g-reduce (r18).
// Compaction -> full permutation idxb; inactive tiles zero-fill + exit (r21).
// Two-pivot GJ prep, 32 barrier rounds (r22 — r24's 4-pivot regressed).
// Main: 4 waves/block, 19-chunk chain each (r23 — best at 54.5us).
// FINAL: r23 configuration. Ledger 588 -> 54.5us; every win was a work or
// serial-depth cut (f16 build, symmetry, MFMA trim, mask compaction, 2-pivot
// GJ); all latency/overlap restructures were null (addressing r13, registers
// r15, forced occupancy r11, L1 pairing r16, LDS ring r17, chain split r23~2).
// ---------------------------------------------------------------------------

#define BT_TOTAL 32768
#define BT_BLK 16
#define NCHUNK 76

typedef _Float16 f16;
typedef __attribute__((ext_vector_type(8))) _Float16 f16x8;
typedef __attribute__((ext_vector_type(4))) _Float16 f16x4;
typedef __attribute__((ext_vector_type(2))) _Float16 h2;
typedef __attribute__((ext_vector_type(4))) float f32x4;
typedef struct { h2 p[4]; } h2q;

#if __has_builtin(__builtin_amdgcn_fdot2)
#define DOT2(a, b, c) __builtin_amdgcn_fdot2((a), (b), (c), false)
#else
#define DOT2(a, b, c) fmaf((float)(a)[0], (float)(b)[0], fmaf((float)(a)[1], (float)(b)[1], (c)))
#endif

// pair-block tables (bJ outer 0..7, bI inner 0..bJ), +1 guard entry
__constant__ unsigned char PB_BJ[37] =
  {0, 1,1, 2,2,2, 3,3,3,3, 4,4,4,4,4, 5,5,5,5,5,5, 6,6,6,6,6,6,6, 7,7,7,7,7,7,7,7, 7};
__constant__ unsigned char PB_BI[37] =
  {0, 0,1, 0,1,2, 0,1,2,3, 0,1,2,3,4, 0,1,2,3,4,5, 0,1,2,3,4,5,6, 0,1,2,3,4,5,6,7, 7};

__device__ __forceinline__ float digammaf_(float x){
  float r = 0.f;
  while (x < 6.f){ r -= 1.f / x; x += 1.f; }
  float xi = 1.f / x;
  float xi2 = xi * xi;
  return r + logf(x) - 0.5f * xi
         - xi2 * (0.083333333333f - xi2 * (0.0083333333333f - xi2 * 0.0039682539683f));
}

__device__ __forceinline__ float wsum64(float x){
  #pragma unroll
  for (int o = 32; o > 0; o >>= 1) x += __shfl_down(x, o);
  return x;  // valid in lane 0
}

// ---------- kernel A: per-k prep (blocks 0..32) + mask compact (block 33) ---
__global__ __launch_bounds__(256) void prep_kernel(
    const float* __restrict__ mu_k, const float* __restrict__ Psi,
    const float* __restrict__ nu_a, const float* __restrict__ kap_a,
    const unsigned char* __restrict__ maskb,
    f16* __restrict__ BG, float* __restrict__ c0o,
    int* __restrict__ nactp, int* __restrict__ idxb)
{
  const int tid = threadIdx.x;

  if (blockIdx.x == 33){
    // ---- mask compaction: full permutation (active then inactive) ----
    __shared__ int cnts[256];
    const int l = tid & 63;
    const bool byteMask =
        __any((maskb[4 * l + 1] | maskb[4 * l + 2] | maskb[4 * l + 3]) != 0);
    unsigned int nz[32];            // bit s of nz[j] = flag of bt 4j+s
    int cnt = 0;
    if (byteMask){
      const uint4* mv = (const uint4*)(maskb + (size_t)tid * 128);
      #pragma unroll
      for (int j = 0; j < 8; ++j){
        uint4 v = mv[j];
        unsigned int w0 = v.x, w1 = v.y, w2 = v.z, w3 = v.w;
        unsigned int b0 = ((w0 & 0xFFu) != 0) | (((w0 & 0xFF00u) != 0) << 1)
                        | (((w0 & 0xFF0000u) != 0) << 2) | (((w0 & 0xFF000000u) != 0) << 3);
        unsigned int b1 = ((w1 & 0xFFu) != 0) | (((w1 & 0xFF00u) != 0) << 1)
                        | (((w1 & 0xFF0000u) != 0) << 2) | (((w1 & 0xFF000000u) != 0) << 3);
        unsigned int b2 = ((w2 & 0xFFu) != 0) | (((w2 & 0xFF00u) != 0) << 1)
                        | (((w2 & 0xFF0000u) != 0) << 2) | (((w2 & 0xFF000000u) != 0) << 3);
        unsigned int b3 = ((w3 & 0xFFu) != 0) | (((w3 & 0xFF00u) != 0) << 1)
                        | (((w3 & 0xFF0000u) != 0) << 2) | (((w3 & 0xFF000000u) != 0) << 3);
        nz[4 * j + 0] = b0; nz[4 * j + 1] = b1; nz[4 * j + 2] = b2; nz[4 * j + 3] = b3;
        cnt += __popc(b0) + __popc(b1) + __popc(b2) + __popc(b3);
      }
    } else {
      const uint4* mv = (const uint4*)maskb + (size_t)tid * 32;
      #pragma unroll
      for (int j = 0; j < 32; ++j){
        uint4 v = mv[j];
        unsigned int b = (v.x != 0) | ((v.y != 0) << 1)
                       | ((v.z != 0) << 2) | ((v.w != 0) << 3);
        nz[j] = b;
        cnt += __popc(b);
      }
    }
    cnts[tid] = cnt;
    __syncthreads();
    for (int off = 1; off < 256; off <<= 1){
      int v = cnts[tid];
      int u = (tid >= off) ? cnts[tid - off] : 0;
      __syncthreads();
      cnts[tid] = v + u;
      __syncthreads();
    }
    const int nact = cnts[255];
    const int base = tid * 128;
    int wofsA = cnts[tid] - cnt;               // exclusive active offset
    int wofsI = nact + base - wofsA;           // exclusive inactive offset
    #pragma unroll
    for (int j = 0; j < 32; ++j){
      unsigned int b = nz[j];
      #pragma unroll
      for (int s = 0; s < 4; ++s){
        const int bt = base + 4 * j + s;
        if (b & (1u << s)) idxb[wofsA++] = bt;
        else               idxb[wofsI++] = bt;
      }
    }
    if (tid == 255) *nactp = nact;
    return;
  }

  const int k = blockIdx.x;
  const int row = tid & 63;
  const int ch  = tid >> 6;        // column chunk: cols [ch*32, ch*32+32) of 128
  const int c0  = ch << 5;

  __shared__ float prA[2][128];
  __shared__ float prB[2][128];
  __shared__ float fcA[2][64];
  __shared__ float fcB[2][64];
  __shared__ float diag[64];
  __shared__ float muk[64];
  __shared__ float vpart[2][64];
  __shared__ float Ediag[64];

  float Wr[32];
  if (ch < 2){
    const float* Pg = Psi + (size_t)k * 4096 + (size_t)row * 64 + c0;
    #pragma unroll
    for (int c = 0; c < 32; ++c) Wr[c] = Pg[c];
  } else {
    #pragma unroll
    for (int c = 0; c < 32; ++c) Wr[c] = ((c0 - 64 + c) == row) ? 1.f : 0.f;
  }
  if (tid < 64) muk[tid] = mu_k[k * 64 + tid];
  if (row == 0){
    #pragma unroll
    for (int c = 0; c < 32; ++c) prA[0][c0 + c] = Wr[c];
  }
  if (row == 1){
    #pragma unroll
    for (int c = 0; c < 32; ++c) prB[0][c0 + c] = Wr[c];
  }
  if (ch == 0){ fcA[0][row] = Wr[0]; fcB[0][row] = Wr[1]; }
  __syncthreads();

  // ---- two-pivot Gauss-Jordan: 32 barrier rounds ----
  #pragma unroll
  for (int jh = 0; jh < 2; ++jh){
    #pragma unroll
    for (int ml = 0; ml < 16; ++ml){
      const int m = jh * 16 + ml;
      const int j = 2 * m;
      const int cur = m & 1, nxt = cur ^ 1;
      const float pivA = prA[cur][j];
      const float rA1  = prA[cur][j + 1];
      const float rcpA = __builtin_amdgcn_rcpf(pivA);
      const float fJ1  = fcA[cur][j + 1] * rcpA;
      const float pivB = fmaf(-fJ1, rA1, prB[cur][j + 1]);
      const float rcpB = __builtin_amdgcn_rcpf(pivB);
      const float f1 = (row == j) ? 0.f : fcA[cur][row] * rcpA;
      const float v1 = (row == j) ? rA1 : fmaf(-f1, rA1, fcB[cur][row]);
      const float f2 = (row == j + 1) ? 0.f : v1 * rcpB;
      const float coefA = fmaf(-f2, fJ1, f1);
      const float coefB = f2;
      if (tid == 0){ diag[j] = pivA; diag[j + 1] = pivB; }
      #pragma unroll
      for (int c = 0; c < 32; ++c)
        Wr[c] = fmaf(-coefA, prA[cur][c0 + c],
                fmaf(-coefB, prB[cur][c0 + c], Wr[c]));
      if (m < 31){
        const int jn2 = j + 2, jn3 = j + 3;
        if (row == jn2){
          #pragma unroll
          for (int c = 0; c < 32; ++c) prA[nxt][c0 + c] = Wr[c];
        }
        if (row == jn3){
          #pragma unroll
          for (int c = 0; c < 32; ++c) prB[nxt][c0 + c] = Wr[c];
        }
        if (ch == (jn2 >> 5)) fcA[nxt][row] = Wr[jn2 & 31];
        if (ch == (jn3 >> 5)) fcB[nxt][row] = Wr[jn3 & 31];
      }
      __syncthreads();
    }
  }

  const float nu = nu_a[k];
  const int j_k = k >> 4, kck = k & 15;

  if (ch >= 2){
    const int h = ch - 2;                   // e-half this thread owns
    const float dinv = nu / diag[row];
    float vp = 0.f;
    #pragma unroll
    for (int c = 0; c < 32; ++c) vp = fmaf(Wr[c], muk[h * 32 + c], vp);
    vpart[h][row] = vp * dinv;
    // E-row scatter into symmetric pair-block layout (only bI <= bJ stored)
    const int d = row;
    const int bI = d >> 3;
    const int pch = (d >> 2) & 1;
    const int sHi = d & 3;                  // g-slot
    #pragma unroll
    for (int cc = 0; cc < 32; ++cc){
      const int e = h * 32 + cc;
      const int bJ = e >> 3;
      float val = Wr[cc] * dinv;
      if (e == d) Ediag[row] = val;
      if (bI <= bJ){
        const int pb = ((bJ * (bJ + 1)) >> 1) + bI;
        const int ci = pb * 2 + pch;
        const float sc = (bI < bJ) ? 2.f : 1.f;
        BG[(size_t)((ci * 3 + j_k) * 64 + kck * 4 + sHi) * 8 + (e & 7)] = (f16)(val * sc);
      }
    }
  }
  __syncthreads();

  if (tid < 64){
    const int t = tid;
    float v = vpart[0][t] + vpart[1][t];
    const int g = (t >> 3) & 3, q = t & 7;
    const int cA = 72 + (t >> 5);
    const int cB = 74 + (t >> 5);
    BG[(size_t)((cA * 3 + j_k) * 64 + kck * 4 + g) * 8 + q] = (f16)(-2.f * v);
    BG[(size_t)((cB * 3 + j_k) * 64 + kck * 4 + g) * 8 + q] = (f16)(Ediag[t]);
    float c2 = wsum64(v * muk[t]);
    float dg = wsum64(digammaf_((nu - (float)t) * 0.5f));
    float ld = wsum64(logf(diag[t]));
    if (t == 0){
      const float LN2   = 0.69314718055994531f;
      const float LN2PI = 1.83787706640934548f;
      float Elogdet = dg + 64.f * LN2 - ld;
      float cst = 0.5f * (Elogdet - 64.f * LN2PI);
      c0o[k] = cst - 0.5f * c2 - 32.f / kap_a[k];
    }
  }
}

// -------- kernel B: main (f16 MFMA x2 + k32 dot, 4-wave, compacted) ---------
#define BUILD(AF, FD, MUD)                                                 \
  {                                                                        \
    float s_[8];                                                           \
    _Pragma("unroll")                                                      \
    for (int q_ = 0; q_ < 8; ++q_) s_[q_] = (MUD) * mue[q_];               \
    _Pragma("unroll")                                                      \
    for (int r_ = 0; r_ < 4; ++r_){                                        \
      h2 fp_ = { (FD)[2 * r_], (FD)[2 * r_ + 1] };                         \
      _Pragma("unroll")                                                    \
      for (int q_ = 0; q_ < 8; ++q_){                                      \
        h2 ep_ = { FeT[q_][2 * r_], FeT[q_][2 * r_ + 1] };                 \
        s_[q_] = DOT2(fp_, ep_, s_[q_]);                                   \
      }                                                                    \
    }                                                                      \
    _Pragma("unroll")                                                      \
    for (int q_ = 0; q_ < 8; ++q_) (AF)[q_] = (f16)s_[q_];                 \
  }

#define MFMA2(AF, B0, B1)                                                  \
  acc0 = __builtin_amdgcn_mfma_f32_16x16x32_f16((AF), (B0), acc0, 0, 0, 0);\
  acc1 = __builtin_amdgcn_mfma_f32_16x16x32_f16((AF), (B1), acc1, 0, 0, 0);

#define K32DOT(AF, B32)                                                    \
  {                                                                        \
    h2q afq_ = __builtin_bit_cast(h2q, (AF));                              \
    h2q bq_  = __builtin_bit_cast(h2q, (B32));                             \
    _Pragma("unroll")                                                      \
    for (int r_ = 0; r_ < 4; ++r_)                                         \
      acc32 = DOT2(afq_.p[r_], bq_.p[r_], acc32);                          \
  }

__global__ __launch_bounds__(256, 2) void main_kernel(
    const float* __restrict__ mu_t, const float* __restrict__ var_t,
    const float* __restrict__ F_t,
    const f16* __restrict__ BG, const float* __restrict__ c0o,
    const int* __restrict__ nactp, const int* __restrict__ idxb,
    float* __restrict__ out)
{
  __shared__ __align__(16) f16 sG[BT_BLK][64][8];  // F[d][r], d^(bt&7); 16384 B
  __shared__ __align__(16) f16 sMu[BT_BLK][64];    // block-8 d-swizzle;  2048 B
  __shared__ int sIdx[BT_BLK];

  const int tid = threadIdx.x;
  const int l = tid & 63;
  const int w = tid >> 6;                // wave = pair-range quarter (0..3)
  const int g = l >> 4;
  const int kc = l & 15;
  const int btl = kc;                    // this lane's local A row
  const int btSw = btl & 7;

  const int nact = *nactp;
  const int t0 = blockIdx.x * BT_BLK;
  const int nLoc = min(BT_BLK, max(0, nact - t0));   // active rows in tile

  if (tid < BT_BLK) sIdx[tid] = idxb[t0 + tid];      // full list: always valid
  __syncthreads();

  // ---- zero-fill inactive rows of this tile (rows nLoc..16) ----
  for (int i = tid; i < (BT_BLK - nLoc) * 33; i += 256){
    const int r = nLoc + i / 33;
    out[(size_t)sIdx[r] * 33 + (i % 33)] = 0.f;
  }
  if (nLoc == 0) return;                 // fully inactive tile: done

  // ---- stage F / mu into LDS (coalesced per row, f32->f16, via idx) ----
  {
    #pragma unroll
    for (int ii = 0; ii < 8; ++ii){
      int i = tid + ii * 256;
      int bt = i >> 7, rem = i & 127, d = rem >> 1, rb = (rem & 1) << 2;
      const float4* fg = (const float4*)(F_t + (size_t)sIdx[bt] * 512);
      float4 f = fg[rem];
      int dsw = d ^ (bt & 7);
      f16x4 ff = { (f16)f.x, (f16)f.y, (f16)f.z, (f16)f.w };
      *(f16x4*)&sG[bt][dsw][rb] = ff;
    }
    {
      int i = tid;                       // 256 float4 = 16 rows x 16
      int bt = i >> 4, e4 = i & 15, d0 = e4 << 2;
      const float4* mg = (const float4*)(mu_t + (size_t)sIdx[bt] * 64);
      float4 m4 = mg[e4];
      int dsw = (((d0 >> 3) ^ (bt & 7)) << 3) | (d0 & 7);
      f16x4 mm = { (f16)m4.x, (f16)m4.y, (f16)m4.z, (f16)m4.w };
      *(f16x4*)&sMu[bt][dsw] = mm;
    }
  }
  __syncthreads();

  // per-wave pair range: wave w = pairs [9w, 9w+9), ext chunk 72+w
  const int ppStart = 9 * w;
  const int ppEnd   = ppStart + 9;

  f32x4 acc0 = {0.f,0.f,0.f,0.f}, acc1 = {0.f,0.f,0.f,0.f};
  float acc32 = 0.f;

  f16x8 FeT[8];      // F rows e = bJ*8+q (reloaded per bJ)
  float mue[8];

  const f16* bp   = BG + (size_t)(ppStart * 2) * 1536 + (size_t)(kc * 4 + g) * 8;
  const f16* bp32 = BG + (size_t)(ppStart * 2) * 1536 + 1024 + (size_t)g * 8;

  // prologue: stage A = chunk 2*ppStart, stage B = chunk 2*ppStart+1
  const int bI0 = PB_BI[ppStart];
  f16x8 fdA = *(const f16x8*)&sG[btl][(bI0 * 8 + g) ^ btSw][0];
  f16x8 fdB = *(const f16x8*)&sG[btl][(bI0 * 8 + 4 + g) ^ btSw][0];
  float mudA = (float)sMu[btl][((bI0 ^ btSw) << 3) | g];
  float mudB = (float)sMu[btl][((bI0 ^ btSw) << 3) | (4 + g)];

  f16x8 a0 = *(const f16x8*)(bp);
  f16x8 a1 = *(const f16x8*)(bp + 512);
  f16x8 b0v = *(const f16x8*)(bp + 1536);
  f16x8 b1v = *(const f16x8*)(bp + 1536 + 512);
  f16x8 w0v = *(const f16x8*)(bp32);
  f16x8 w1v = *(const f16x8*)(bp32 + 1536);
  bp += 3072;
  bp32 += 3072;

  int curBJ = -1;
  for (int pp = ppStart; pp < ppEnd; ++pp){
    const int bJ = PB_BJ[pp];
    if (bJ != curBJ){
      curBJ = bJ;
      #pragma unroll
      for (int q = 0; q < 8; ++q)
        FeT[q] = *(const f16x8*)&sG[btl][((bJ << 3) + q) ^ btSw][0];
      f16x8 mr = *(const f16x8*)&sMu[btl][((bJ ^ btSw) << 3)];
      #pragma unroll
      for (int q = 0; q < 8; ++q) mue[q] = (float)mr[q];
    }
    const int bIn = PB_BI[pp + 1];
    // ---- even chunk (stage A), refill with next pair's p=0 ----
    {
      f16x8 af;
      BUILD(af, fdA, mudA);
      MFMA2(af, a0, a1);
      K32DOT(af, w0v);
      a0 = *(const f16x8*)(bp);
      a1 = *(const f16x8*)(bp + 512);
      w0v = *(const f16x8*)(bp32);
      fdA = *(const f16x8*)&sG[btl][(bIn * 8 + g) ^ btSw][0];
      mudA = (float)sMu[btl][((bIn ^ btSw) << 3) | g];
    }
    // ---- odd chunk (stage B), refill with next pair's p=1 ----
    {
      f16x8 af;
      BUILD(af, fdB, mudB);
      MFMA2(af, b0v, b1v);
      K32DOT(af, w1v);
      b0v = *(const f16x8*)(bp + 1536);
      b1v = *(const f16x8*)(bp + 1536 + 512);
      w1v = *(const f16x8*)(bp32 + 1536);
      fdB = *(const f16x8*)&sG[btl][(bIn * 8 + 4 + g) ^ btSw][0];
      mudB = (float)sMu[btl][((bIn ^ btSw) << 3) | (4 + g)];
    }
    bp += 3072;
    bp32 += 3072;
  }

  // ---- ext chunk 72+w (one per wave), ABSOLUTE addressing ----
  {
    const f16* bpe   = BG + (size_t)(72 + w) * 1536 + (size_t)(kc * 4 + g) * 8;
    const f16* bpe32 = BG + (size_t)(72 + w) * 1536 + 1024 + (size_t)g * 8;
    f16x8 af;
    if (w < 2){
      af = *(const f16x8*)&sMu[btl][(((w * 4 + g) ^ btSw) << 3)];
    } else {
      const float* vr = var_t + (size_t)sIdx[btl] * 64 + (w - 2) * 32 + g * 8;
      f32x4 va = *(const f32x4*)(vr);
      f32x4 vb = *(const f32x4*)(vr + 4);
      #pragma unroll
      for (int r = 0; r < 4; ++r){ af[r] = (f16)va[r]; af[4 + r] = (f16)vb[r]; }
    }
    f16x8 e0 = *(const f16x8*)(bpe);
    f16x8 e1 = *(const f16x8*)(bpe + 512);
    f16x8 e32 = *(const f16x8*)(bpe32);
    MFMA2(af, e0, e1);
    K32DOT(af, e32);
  }

  // ---- cross-wave reduce (aliased into sG after barrier) ----
  __syncthreads();                         // all waves done reading sG/sMu
  float* sRedF = (float*)sG;               // [3][64][9] floats = 6912 B
  if (w > 0){
    const int bofs = ((w - 1) * 64 + l) * 9;
    #pragma unroll
    for (int r = 0; r < 4; ++r){
      sRedF[bofs + r]     = acc0[r];
      sRedF[bofs + 4 + r] = acc1[r];
    }
    sRedF[bofs + 8] = acc32;
  }
  __syncthreads();
  if (w == 0){
    #pragma unroll
    for (int ww = 0; ww < 3; ++ww){
      const int bofs = (ww * 64 + l) * 9;
      #pragma unroll
      for (int r = 0; r < 4; ++r){
        acc0[r] += sRedF[bofs + r];
        acc1[r] += sRedF[bofs + 4 + r];
      }
      acc32 += sRedF[bofs + 8];
    }
    // g-reduce k32 (lanes same kc, different g)
    acc32 += __shfl_xor(acc32, 16);
    acc32 += __shfl_xor(acc32, 32);

    float c0a = c0o[kc];
    float c0b = c0o[16 + kc];
    float c0c = c0o[32];
    #pragma unroll
    for (int reg = 0; reg < 4; ++reg){
      int r16 = g * 4 + reg;
      if (r16 < nLoc){
        float* op = out + (size_t)sIdx[r16] * 33;
        op[kc]      = fmaf(-0.5f, acc0[reg], c0a);
        op[16 + kc] = fmaf(-0.5f, acc1[reg], c0b);
      }
    }
    if (g == 0 && kc < nLoc){
      out[(size_t)sIdx[kc] * 33 + 32] = fmaf(-0.5f, acc32, c0c);
    }
  }
}

// --------------------------- launch -----------------------------------------
extern "C" void kernel_launch(void* const* d_in, const int* in_sizes, int n_in,
                              void* d_out, int out_size, void* d_ws, size_t ws_size,
                              hipStream_t stream)
{
  const float* mu_t  = (const float*)d_in[0];
  const float* var_t = (const float*)d_in[1];
  const float* F_t   = (const float*)d_in[2];
  const float* mu_k  = (const float*)d_in[3];
  const float* Psi   = (const float*)d_in[4];
  const float* nu    = (const float*)d_in[5];
  const float* kap   = (const float*)d_in[6];
  const unsigned char* mask = (const unsigned char*)d_in[7];

  f16*   BG   = (f16*)d_ws;                             // 233472 B
  float* c0o  = (float*)((char*)d_ws + 233472);         // 132 B
  int*   nact = (int*)((char*)d_ws + 233472 + 256);     // 4 B
  int*   idxb = nact + 1;                               // 131072 B
  float* outp = (float*)d_out;

  hipLaunchKernelGGL(prep_kernel, dim3(34), dim3(256), 0, stream,
                     mu_k, Psi, nu, kap, mask, BG, c0o, nact, idxb);
  hipLaunchKernelGGL(main_kernel, dim3(BT_TOTAL / BT_BLK), dim3(256), 0, stream,
                     mu_t, var_t, F_t, BG, c0o, nact, idxb, outp);
}